// Round 3
// baseline (1524.044 us; speedup 1.0000x reference)
//
#include <hip/hip_runtime.h>
#include <math.h>

// Problem constants
#define BBATCH 8
#define CC 96
#define HH 224
#define NHW 32            // 224/7 windows per side
#define NWIN 1024
#define TOPK 256
#define PERK 24
#define DST 16
#define DTR 6
#define LL 12544          // 256*49
#define LC 98             // chunk length per block (2 windows, 2 sub-chunks of 49)
#define LCP 52            // padded sub-chunk row length (49 used + 3 zero pad)
#define NG 13             // float4 groups per row
#define TCH 128           // chunks per (b,k): 128*98 = 12544
#define NBK 32            // B*4 directions

// workspace offsets (floats) — total 5,539,072 floats = 22.2 MB
#define OFF_POOL 0
#define OFF_LOG  786432
#define OFF_PROB 794624
#define OFF_RW   802816
#define OFF_RANK 804864
#define OFF_SEL  813056
#define OFF_WEFF 815104
#define OFF_CP   820480
#define OFF_CS   2393344
#define OFF_HIN  3966208

// DPP row_ror:N add — 16-lane full-sum reduction on the VALU pipe (not DS)
#define ROR_ADD(v, CTRL) \
    v += __int_as_float(__builtin_amdgcn_update_dpp(0, __float_as_int(v), CTRL, 0xf, 0xf, true))

// -------- K0: fold dt_proj into x_proj: Wcomb[k][56][24] --------
// rows 0..23  : W_eff[d][c] = sum_r dtw[k][d][r]*xpw[k][r][c]   (delta path)
// rows 24..39 : xpw[k][6+..][c]                                  (B path)
// rows 40..55 : xpw[k][22+..][c]                                 (C path)
__global__ void k_weff(const float* __restrict__ xpw, const float* __restrict__ dtw,
                       float* __restrict__ wcomb) {
    int i = blockIdx.x * blockDim.x + threadIdx.x;
    if (i >= 4 * 56 * PERK) return;
    int k = i / (56 * PERK), rem = i - k * (56 * PERK);
    int row = rem / PERK, c = rem - row * PERK;
    float v;
    if (row < PERK) {
        v = 0.f;
        #pragma unroll
        for (int r = 0; r < DTR; ++r)
            v += dtw[(k * PERK + row) * DTR + r] * xpw[(k * 38 + r) * PERK + c];
    } else {
        v = xpw[(k * 38 + (row - PERK + DTR)) * PERK + c];
    }
    wcomb[i] = v;
}

// -------- K1: window pooling: pooledT[b][c][w] --------
__global__ void k_pool(const float* __restrict__ x, float* __restrict__ pooled) {
    int bc = blockIdx.x;                 // b*96+c
    const float* xp = x + (size_t)bc * HH * HH;
    float* pp = pooled + (size_t)bc * NWIN;
    for (int w = threadIdx.x; w < NWIN; w += blockDim.x) {
        int wr = w >> 5, wc = w & 31;
        const float* base = xp + (wr * 7) * HH + wc * 7;
        float s = 0.f;
        #pragma unroll
        for (int i = 0; i < 7; ++i) {
            #pragma unroll
            for (int j = 0; j < 7; ++j) s += base[i * HH + j];
        }
        pp[w] = s * (1.0f / 49.0f);
    }
}

// -------- K2: router MLP -> logits --------
__global__ void k_router(const float* __restrict__ pooled,
                         const float* __restrict__ w1, const float* __restrict__ b1,
                         const float* __restrict__ w2, const float* __restrict__ b2,
                         float* __restrict__ logits) {
    __shared__ float sw1[PERK * CC];
    __shared__ float sb1[PERK];
    __shared__ float sw2[PERK];
    for (int i = threadIdx.x; i < PERK * CC; i += blockDim.x) sw1[i] = w1[i];
    if (threadIdx.x < PERK) { sb1[threadIdx.x] = b1[threadIdx.x]; sw2[threadIdx.x] = w2[threadIdx.x]; }
    __syncthreads();
    int gid = blockIdx.x * blockDim.x + threadIdx.x;   // 8192 threads
    int b = gid >> 10, w = gid & 1023;
    float hid[PERK];
    #pragma unroll
    for (int j = 0; j < PERK; ++j) hid[j] = sb1[j];
    const float* pp = pooled + (size_t)b * CC * NWIN + w;
    for (int c = 0; c < CC; ++c) {
        float pv = pp[(size_t)c * NWIN];
        #pragma unroll
        for (int j = 0; j < PERK; ++j) hid[j] += pv * sw1[j * CC + c];
    }
    float lg = b2[0];
    #pragma unroll
    for (int j = 0; j < PERK; ++j) {
        float hv = hid[j];
        float g = 0.5f * hv * (1.0f + erff(hv * 0.7071067811865476f));
        lg += g * sw2[j];
    }
    logits[gid] = lg;
}

// -------- K3: softmax over 1024 windows + stable descending rank --------
__global__ void k_rank(const float* __restrict__ logits, float* __restrict__ probs,
                       float* __restrict__ rw, int* __restrict__ rank, int* __restrict__ sel) {
    __shared__ __attribute__((aligned(16))) float sp[NWIN];
    __shared__ float red[NWIN];
    int b = blockIdx.x, t = threadIdx.x;
    float lg = logits[b * NWIN + t];
    red[t] = lg; __syncthreads();
    for (int o = 512; o > 0; o >>= 1) { if (t < o) red[t] = fmaxf(red[t], red[t + o]); __syncthreads(); }
    float mx = red[0]; __syncthreads();
    float e = expf(lg - mx);
    red[t] = e; __syncthreads();
    for (int o = 512; o > 0; o >>= 1) { if (t < o) red[t] += red[t + o]; __syncthreads(); }
    float p = e / red[0];
    sp[t] = p;
    probs[b * NWIN + t] = p;
    __syncthreads();
    int r = 0;
    for (int j = 0; j < NWIN; j += 4) {
        float4 pj = *(const float4*)&sp[j];
        r += (int)((pj.x > p) || (pj.x == p && (j + 0) < t));
        r += (int)((pj.y > p) || (pj.y == p && (j + 1) < t));
        r += (int)((pj.z > p) || (pj.z == p && (j + 2) < t));
        r += (int)((pj.w > p) || (pj.w == p && (j + 3) < t));
    }
    rank[b * NWIN + t] = r;
    if (r < TOPK) { sel[b * TOPK + r] = t; rw[b * TOPK + r] = p; }
}

// scan-position l -> grid (a=row,b2=col) and pixel (wi,wj), per direction k
__device__ __forceinline__ void decode_l(int k, int l, int& a, int& b2, int& wi, int& wj) {
    int u = (k >= 2) ? (LL - 1 - l) : l;
    int q = u / 49, pix = u - q * 49;
    if ((k & 1) == 0) { a = q >> 4; b2 = q & 15; wi = pix / 7; wj = pix - wi * 7; }
    else             { b2 = q >> 4; a = q & 15; wj = pix / 7; wi = pix - wj * 7; }
}

// softplus, exact enough vs threshold
__device__ __forceinline__ float softplus_f(float v) {
    return fmaxf(v, 0.f) + log1pf(__expf(-fabsf(v)));
}

// -------- K4: phase-1 chunk scan: per-chunk (P = prod a, S = local state) --------
__global__ __launch_bounds__(384, 8) void k_phase1(
        const float* __restrict__ x, const float* __restrict__ wcomb,
        const float* __restrict__ dtb, const float* __restrict__ alogs,
        const int* __restrict__ sel,
        float* __restrict__ carrP, float* __restrict__ carrS) {
    __shared__ __attribute__((aligned(16))) float sxs[PERK][LCP];
    __shared__ __attribute__((aligned(16))) float sdelta[PERK][LCP];
    __shared__ __attribute__((aligned(16))) float sB[DST][LCP];
    __shared__ float swt[40 * PERK];
    __shared__ float sbias[PERK];
    int blk = blockIdx.x;               // bk*TCH + t
    int t = blk % TCH; int bk = blk / TCH; int k = bk & 3; int b = bk >> 2;
    int tid = threadIdx.x;
    for (int i = tid; i < 40 * PERK; i += 384) swt[i] = wcomb[k * (56 * PERK) + i];
    if (tid < PERK) sbias[tid] = dtb[k * PERK + tid];
    // zero pad columns 49..51 (never overwritten afterwards)
    if (tid < 192) {
        int r = tid / 3, j = 49 + tid % 3;
        if (r < 24) sxs[r][j] = 0.f;
        else if (r < 48) sdelta[r - 24][j] = 0.f;
        else sB[r - 48][j] = 0.f;
    }
    int d = tid >> 4, s = tid & 15;
    float A = -__expf(alogs[(k * PERK + d) * DST + s]);
    float P = 1.f, S = 0.f;
    #pragma unroll 1
    for (int si = 0; si < 2; ++si) {
        int l0 = t * LC + si * 49;
        for (int idx = tid; idx < PERK * 49; idx += 384) {
            int d2 = idx / 49, j = idx - d2 * 49;
            int a, b2, wi, wj; decode_l(k, l0 + j, a, b2, wi, wj);
            int wsel = sel[b * TOPK + a * 16 + b2];
            int gi = (wsel >> 5) * 7 + wi, gj = (wsel & 31) * 7 + wj;
            sxs[d2][j] = x[(((size_t)b * CC + (4 * d2 + k)) * HH + gi) * HH + gj];
        }
        __syncthreads();
        // fused projection: rows 0..23 -> softplus(Weff*xs+bias)=delta, rows 24..39 -> B
        for (int idx = tid; idx < 40 * NG; idx += 384) {
            int row = idx / NG, g = idx - row * NG; int j = g * 4;
            float bs = (row < PERK) ? sbias[row] : 0.f;
            float ax = bs, ay = bs, az = bs, aw = bs;
            #pragma unroll
            for (int d2 = 0; d2 < PERK; ++d2) {
                float w = swt[row * PERK + d2];
                float4 v = *(const float4*)&sxs[d2][j];
                ax += w * v.x; ay += w * v.y; az += w * v.z; aw += w * v.w;
            }
            float* dst;
            if (row < PERK) {
                ax = softplus_f(ax); ay = softplus_f(ay); az = softplus_f(az); aw = softplus_f(aw);
                dst = &sdelta[row][j];
            } else dst = &sB[row - PERK][j];
            if (g < 12) { float4 o = {ax, ay, az, aw}; *(float4*)dst = o; }
            else dst[0] = ax;
        }
        __syncthreads();
        for (int g = 0; g < NG; ++g) {
            int j = g * 4;
            float4 dl4 = *(const float4*)&sdelta[d][j];   // pads = 0
            float4 xs4 = *(const float4*)&sxs[d][j];      // pads = 0
            float4 B4  = *(const float4*)&sB[s][j];       // pads = 0
            float aa;
            aa = __expf(dl4.x * A); S = aa * S + (dl4.x * xs4.x) * B4.x; P *= aa;
            aa = __expf(dl4.y * A); S = aa * S + (dl4.y * xs4.y) * B4.y; P *= aa;
            aa = __expf(dl4.z * A); S = aa * S + (dl4.z * xs4.z) * B4.z; P *= aa;
            aa = __expf(dl4.w * A); S = aa * S + (dl4.w * xs4.w) * B4.w; P *= aa;
        }
        __syncthreads();   // protect sxs/sdelta/sB for next sub-chunk
    }
    size_t cidx = (size_t)blk * 384 + tid;
    carrP[cidx] = P; carrS[cidx] = S;
}

// -------- K5: carry scan across chunks --------
__global__ void k_carry(const float* __restrict__ carrP, const float* __restrict__ carrS,
                        float* __restrict__ hin) {
    int gid = blockIdx.x * blockDim.x + threadIdx.x;   // 12288
    int bk = gid / 384, ds = gid - bk * 384;
    float Hv = 0.f;
    for (int t = 0; t < TCH; ++t) {
        size_t idx = ((size_t)bk * TCH + t) * 384 + ds;
        hin[idx] = Hv;
        Hv = carrP[idx] * Hv + carrS[idx];
    }
}

// -------- K6: base output: x*(1+p) unselected, x selected --------
__global__ __launch_bounds__(64) void k_base(const float* __restrict__ x,
        const float* __restrict__ probs, const int* __restrict__ rank,
        float* __restrict__ out) {
    int wr = blockIdx.x % NHW; int bc = blockIdx.x / NHW;
    int b = bc / CC;
    __shared__ float buf[7 * HH];
    __shared__ float fmul[NHW];
    int tid = threadIdx.x;
    const float* xp = x + ((size_t)bc * HH + wr * 7) * HH;
    for (int i = tid; i < 7 * HH; i += 64) buf[i] = xp[i];
    if (tid < NHW) {
        int w = wr * NHW + tid;
        fmul[tid] = (rank[b * NWIN + w] < TOPK) ? 1.0f : (1.0f + probs[b * NWIN + w]);
    }
    __syncthreads();
    int c = bc - b * CC;
    for (int idx = tid; idx < NHW * 49; idx += 64) {
        int wc = idx / 49, r = idx - wc * 49;
        int ri = r / 7, rj = r - ri * 7;
        float v = buf[ri * HH + wc * 7 + rj];
        int w = wr * NHW + wc;
        out[(((size_t)b * NWIN + w) * CC + c) * 49 + r] = v * fmul[wc];
    }
}

// -------- K7: phase-3 scan with carry-in + y + inverse permutation + scatter-add --------
__global__ __launch_bounds__(384, 8) void k_scan(
        const float* __restrict__ x, const float* __restrict__ wcomb,
        const float* __restrict__ dtb, const float* __restrict__ alogs,
        const float* __restrict__ dsv, const int* __restrict__ sel,
        const float* __restrict__ rw, const float* __restrict__ hin,
        float* __restrict__ out) {
    __shared__ __attribute__((aligned(16))) float sxs[PERK][LCP];
    __shared__ __attribute__((aligned(16))) float sdelta[PERK][LCP];  // doubles as y after recurrence
    __shared__ __attribute__((aligned(16))) float sB[DST][LCP];
    __shared__ __attribute__((aligned(16))) float sC[DST][LCP];
    __shared__ float swt[56 * PERK];
    __shared__ float sbias[PERK];
    __shared__ int   obase[49];
    __shared__ float srwj[49];
    int blk = blockIdx.x;
    int t = blk % TCH; int bk = blk / TCH; int k = bk & 3; int b = bk >> 2;
    int tid = threadIdx.x;
    for (int i = tid; i < 56 * PERK; i += 384) swt[i] = wcomb[k * (56 * PERK) + i];
    if (tid < PERK) sbias[tid] = dtb[k * PERK + tid];
    // zero pad columns 49..51
    if (tid < 240) {
        int r = tid / 3, j = 49 + tid % 3;
        if (r < 24) sxs[r][j] = 0.f;
        else if (r < 48) sdelta[r - 24][j] = 0.f;
        else if (r < 64) sB[r - 48][j] = 0.f;
        else sC[r - 64][j] = 0.f;
    }
    int d = tid >> 4, s = tid & 15;
    float A = -__expf(alogs[(k * PERK + d) * DST + s]);
    float Dsr = dsv[k * PERK + d];
    size_t cidx = (size_t)blk * 384 + tid;
    float h = hin[cidx];
    #pragma unroll 1
    for (int si = 0; si < 2; ++si) {
        int l0 = t * LC + si * 49;
        if (tid < 49) {
            int a, b2, wi, wj; decode_l(k, l0 + tid, a, b2, wi, wj);
            int lp = ((a * 7 + wi) * 16 + b2) * 7 + wj;          // local_reverse target
            int qo = lp / 49, ro = lp - qo * 49;
            int wsel = sel[b * TOPK + qo];
            obase[tid] = ((b * NWIN + wsel) * CC + k * PERK) * 49 + ro;
            srwj[tid] = rw[b * TOPK + qo];
        }
        for (int idx = tid; idx < PERK * 49; idx += 384) {
            int d2 = idx / 49, j = idx - d2 * 49;
            int a, b2, wi, wj; decode_l(k, l0 + j, a, b2, wi, wj);
            int wsel = sel[b * TOPK + a * 16 + b2];
            int gi = (wsel >> 5) * 7 + wi, gj = (wsel & 31) * 7 + wj;
            sxs[d2][j] = x[(((size_t)b * CC + (4 * d2 + k)) * HH + gi) * HH + gj];
        }
        __syncthreads();
        // fused projection: 0..23 delta (softplus), 24..39 B, 40..55 C
        for (int idx = tid; idx < 56 * NG; idx += 384) {
            int row = idx / NG, g = idx - row * NG; int j = g * 4;
            float bs = (row < PERK) ? sbias[row] : 0.f;
            float ax = bs, ay = bs, az = bs, aw = bs;
            #pragma unroll
            for (int d2 = 0; d2 < PERK; ++d2) {
                float w = swt[row * PERK + d2];
                float4 v = *(const float4*)&sxs[d2][j];
                ax += w * v.x; ay += w * v.y; az += w * v.z; aw += w * v.w;
            }
            float* dst;
            if (row < PERK) {
                ax = softplus_f(ax); ay = softplus_f(ay); az = softplus_f(az); aw = softplus_f(aw);
                dst = &sdelta[row][j];
            } else if (row < PERK + DST) dst = &sB[row - PERK][j];
            else dst = &sC[row - PERK - DST][j];
            if (g < 12) { float4 o = {ax, ay, az, aw}; *(float4*)dst = o; }
            else dst[0] = ax;
        }
        __syncthreads();
        for (int g = 0; g < NG; ++g) {
            int j = g * 4;
            float4 dl4 = *(const float4*)&sdelta[d][j];
            float4 xs4 = *(const float4*)&sxs[d][j];
            float4 B4  = *(const float4*)&sB[s][j];
            float4 C4  = *(const float4*)&sC[s][j];
            float aa, part;
            aa = __expf(dl4.x * A); h = aa * h + (dl4.x * xs4.x) * B4.x;
            part = h * C4.x;
            ROR_ADD(part, 0x121); ROR_ADD(part, 0x122); ROR_ADD(part, 0x124); ROR_ADD(part, 0x128);
            if (s == 0) sdelta[d][j] = part + xs4.x * Dsr;       // j = 4g <= 48, valid
            aa = __expf(dl4.y * A); h = aa * h + (dl4.y * xs4.y) * B4.y;
            part = h * C4.y;
            ROR_ADD(part, 0x121); ROR_ADD(part, 0x122); ROR_ADD(part, 0x124); ROR_ADD(part, 0x128);
            if (s == 0 && j + 1 < 49) sdelta[d][j + 1] = part + xs4.y * Dsr;
            aa = __expf(dl4.z * A); h = aa * h + (dl4.z * xs4.z) * B4.z;
            part = h * C4.z;
            ROR_ADD(part, 0x121); ROR_ADD(part, 0x122); ROR_ADD(part, 0x124); ROR_ADD(part, 0x128);
            if (s == 0 && j + 2 < 49) sdelta[d][j + 2] = part + xs4.z * Dsr;
            aa = __expf(dl4.w * A); h = aa * h + (dl4.w * xs4.w) * B4.w;
            part = h * C4.w;
            ROR_ADD(part, 0x121); ROR_ADD(part, 0x122); ROR_ADD(part, 0x124); ROR_ADD(part, 0x128);
            if (s == 0 && j + 3 < 49) sdelta[d][j + 3] = part + xs4.w * Dsr;
        }
        __syncthreads();
        // scatter-add y (in sdelta) with inverse permutation + rw weight
        for (int idx = tid; idx < PERK * 49; idx += 384) {
            int d2 = idx / 49, j = idx - d2 * 49;
            out[obase[j] + d2 * 49] += sdelta[d2][j] * srwj[j];
        }
        __syncthreads();   // protect obase/srwj/sdelta for next sub-chunk
    }
}

extern "C" void kernel_launch(void* const* d_in, const int* in_sizes, int n_in,
                              void* d_out, int out_size, void* d_ws, size_t ws_size,
                              hipStream_t stream) {
    const float* x   = (const float*)d_in[0];
    const float* w1  = (const float*)d_in[1];
    const float* b1  = (const float*)d_in[2];
    const float* w2  = (const float*)d_in[3];
    const float* b2  = (const float*)d_in[4];
    const float* xpw = (const float*)d_in[5];
    const float* dtw = (const float*)d_in[6];
    const float* dtb = (const float*)d_in[7];
    const float* alg = (const float*)d_in[8];
    const float* dsv = (const float*)d_in[9];
    float* out = (float*)d_out;
    float* ws  = (float*)d_ws;

    float* pooled = ws + OFF_POOL;
    float* logits = ws + OFF_LOG;
    float* probs  = ws + OFF_PROB;
    float* rwv    = ws + OFF_RW;
    int*   rank   = (int*)(ws + OFF_RANK);
    int*   sel    = (int*)(ws + OFF_SEL);
    float* wcomb  = ws + OFF_WEFF;
    float* cP  = ws + OFF_CP;
    float* cS  = ws + OFF_CS;
    float* hin = ws + OFF_HIN;

    k_weff  <<<(4 * 56 * PERK + 255) / 256, 256, 0, stream>>>(xpw, dtw, wcomb);
    k_pool  <<<BBATCH * CC, 256, 0, stream>>>(x, pooled);
    k_router<<<BBATCH * NWIN / 256, 256, 0, stream>>>(pooled, w1, b1, w2, b2, logits);
    k_rank  <<<BBATCH, 1024, 0, stream>>>(logits, probs, rwv, rank, sel);
    k_phase1<<<NBK * TCH, 384, 0, stream>>>(x, wcomb, dtb, alg, sel, cP, cS);
    k_carry <<<48, 256, 0, stream>>>(cP, cS, hin);
    k_base  <<<BBATCH * CC * NHW, 64, 0, stream>>>(x, probs, rank, out);
    k_scan  <<<NBK * TCH, 384, 0, stream>>>(x, wcomb, dtb, alg, dsv, sel, rwv, hin, out);
}

// Round 4
// 1454.859 us; speedup vs baseline: 1.0476x; 1.0476x over previous
//
#include <hip/hip_runtime.h>
#include <math.h>

// Problem constants
#define BBATCH 8
#define CC 96
#define HH 224
#define NHW 32            // 224/7 windows per side
#define NWIN 1024
#define TOPK 256
#define PERK 24
#define DST 16
#define DTR 6
#define LL 12544          // 256*49
#define LC 98             // chunk length per block (2 sub-chunks = 2 scan windows)
#define LCP 52            // padded sub-chunk row length (49 used + 3 zero pad)
#define NG 13             // float4 groups per row
#define TCH 128           // chunks per (b,k): 128*98 = 12544
#define NBK 32            // B*4 directions

// workspace offsets (floats) — total 13,600,000 floats = 54.4 MB
#define OFF_POOL 0
#define OFF_LOG  786432
#define OFF_PROB 794624
#define OFF_RW   802816
#define OFF_RANK 804864
#define OFF_SEL  813056
#define OFF_WEFF 815104
#define OFF_CP   820480      // 1,572,864 floats; ALSO reused as hin (read-before-write in k_carry)
#define OFF_CS   2393344     // 1,572,864 floats
#define OFF_YWS  3966208     // 9,633,792 floats: y_ws[bk][l][d], d innermost

// DPP row_ror:N add — 16-lane full-sum reduction on the VALU pipe (not DS)
#define ROR_ADD(v, CTRL) \
    v += __int_as_float(__builtin_amdgcn_update_dpp(0, __float_as_int(v), CTRL, 0xf, 0xf, true))

// -------- K0: fold dt_proj into x_proj: Wcomb[k][56][24] --------
__global__ void k_weff(const float* __restrict__ xpw, const float* __restrict__ dtw,
                       float* __restrict__ wcomb) {
    int i = blockIdx.x * blockDim.x + threadIdx.x;
    if (i >= 4 * 56 * PERK) return;
    int k = i / (56 * PERK), rem = i - k * (56 * PERK);
    int row = rem / PERK, c = rem - row * PERK;
    float v;
    if (row < PERK) {
        v = 0.f;
        #pragma unroll
        for (int r = 0; r < DTR; ++r)
            v += dtw[(k * PERK + row) * DTR + r] * xpw[(k * 38 + r) * PERK + c];
    } else {
        v = xpw[(k * 38 + (row - PERK + DTR)) * PERK + c];
    }
    wcomb[i] = v;
}

// -------- K1: window pooling: pooledT[b][c][w] --------
__global__ void k_pool(const float* __restrict__ x, float* __restrict__ pooled) {
    int bc = blockIdx.x;                 // b*96+c
    const float* xp = x + (size_t)bc * HH * HH;
    float* pp = pooled + (size_t)bc * NWIN;
    for (int w = threadIdx.x; w < NWIN; w += blockDim.x) {
        int wr = w >> 5, wc = w & 31;
        const float* base = xp + (wr * 7) * HH + wc * 7;
        float s = 0.f;
        #pragma unroll
        for (int i = 0; i < 7; ++i) {
            #pragma unroll
            for (int j = 0; j < 7; ++j) s += base[i * HH + j];
        }
        pp[w] = s * (1.0f / 49.0f);
    }
}

// -------- K2: router MLP -> logits --------
__global__ void k_router(const float* __restrict__ pooled,
                         const float* __restrict__ w1, const float* __restrict__ b1,
                         const float* __restrict__ w2, const float* __restrict__ b2,
                         float* __restrict__ logits) {
    __shared__ float sw1[PERK * CC];
    __shared__ float sb1[PERK];
    __shared__ float sw2[PERK];
    for (int i = threadIdx.x; i < PERK * CC; i += blockDim.x) sw1[i] = w1[i];
    if (threadIdx.x < PERK) { sb1[threadIdx.x] = b1[threadIdx.x]; sw2[threadIdx.x] = w2[threadIdx.x]; }
    __syncthreads();
    int gid = blockIdx.x * blockDim.x + threadIdx.x;   // 8192 threads
    int b = gid >> 10, w = gid & 1023;
    float hid[PERK];
    #pragma unroll
    for (int j = 0; j < PERK; ++j) hid[j] = sb1[j];
    const float* pp = pooled + (size_t)b * CC * NWIN + w;
    for (int c = 0; c < CC; ++c) {
        float pv = pp[(size_t)c * NWIN];
        #pragma unroll
        for (int j = 0; j < PERK; ++j) hid[j] += pv * sw1[j * CC + c];
    }
    float lg = b2[0];
    #pragma unroll
    for (int j = 0; j < PERK; ++j) {
        float hv = hid[j];
        float g = 0.5f * hv * (1.0f + erff(hv * 0.7071067811865476f));
        lg += g * sw2[j];
    }
    logits[gid] = lg;
}

// -------- K3a: softmax over 1024 windows --------
__global__ void k_soft(const float* __restrict__ logits, float* __restrict__ probs) {
    __shared__ float red[NWIN];
    int b = blockIdx.x, t = threadIdx.x;
    float lg = logits[b * NWIN + t];
    red[t] = lg; __syncthreads();
    for (int o = 512; o > 0; o >>= 1) { if (t < o) red[t] = fmaxf(red[t], red[t + o]); __syncthreads(); }
    float mx = red[0]; __syncthreads();
    float e = expf(lg - mx);
    red[t] = e; __syncthreads();
    for (int o = 512; o > 0; o >>= 1) { if (t < o) red[t] += red[t + o]; __syncthreads(); }
    probs[b * NWIN + t] = e / red[0];
}

// -------- K3b: stable descending rank (distributed over 128 blocks) --------
__global__ __launch_bounds__(64) void k_rank2(const float* __restrict__ probs,
        float* __restrict__ rw, int* __restrict__ rank, int* __restrict__ sel) {
    __shared__ __attribute__((aligned(16))) float sp[NWIN];
    int b = blockIdx.x >> 4, slice = blockIdx.x & 15;
    int tid = threadIdx.x;
    for (int i = tid; i < NWIN / 4; i += 64)
        ((float4*)sp)[i] = ((const float4*)(probs + (size_t)b * NWIN))[i];
    __syncthreads();
    int w = slice * 64 + tid;
    float p = sp[w];
    int r = 0;
    for (int j = 0; j < NWIN; j += 4) {
        float4 pj = *(const float4*)&sp[j];
        r += (int)((pj.x > p) || (pj.x == p && (j + 0) < w));
        r += (int)((pj.y > p) || (pj.y == p && (j + 1) < w));
        r += (int)((pj.z > p) || (pj.z == p && (j + 2) < w));
        r += (int)((pj.w > p) || (pj.w == p && (j + 3) < w));
    }
    rank[b * NWIN + w] = r;
    if (r < TOPK) { sel[b * TOPK + r] = w; rw[b * TOPK + r] = p; }
}

// softplus
__device__ __forceinline__ float softplus_f(float v) {
    return fmaxf(v, 0.f) + log1pf(__expf(-fabsf(v)));
}

// per-sub-chunk selected-window lookup: sub-chunk = exactly one scan window
__device__ __forceinline__ int subchunk_wsel(const int* sel, int b, int k, int t, int si) {
    int qscan = 2 * t + si;
    if (k >= 2) qscan = 255 - qscan;
    int selidx = (k & 1) ? (((qscan & 15) << 4) | (qscan >> 4)) : qscan;
    return sel[b * TOPK + selidx];
}

// -------- K4: phase-1 chunk scan: per-chunk (P = prod a, S = local state) --------
__global__ __launch_bounds__(384, 8) void k_phase1(
        const float* __restrict__ x, const float* __restrict__ wcomb,
        const float* __restrict__ dtb, const float* __restrict__ alogs,
        const int* __restrict__ sel,
        float* __restrict__ carrP, float* __restrict__ carrS) {
    __shared__ __attribute__((aligned(16))) float sxs[PERK][LCP];
    __shared__ __attribute__((aligned(16))) float sdelta[PERK][LCP];
    __shared__ __attribute__((aligned(16))) float sB[DST][LCP];
    __shared__ float swt[40 * PERK];
    __shared__ float sbias[PERK];
    int blk = blockIdx.x;               // bk*TCH + t
    int t = blk % TCH; int bk = blk / TCH; int k = bk & 3; int b = bk >> 2;
    int tid = threadIdx.x;
    for (int i = tid; i < 40 * PERK; i += 384) swt[i] = wcomb[k * (56 * PERK) + i];
    if (tid < PERK) sbias[tid] = dtb[k * PERK + tid];
    if (tid < 192) {                    // zero pad columns 49..51
        int r = tid / 3, j = 49 + tid % 3;
        if (r < 24) sxs[r][j] = 0.f;
        else if (r < 48) sdelta[r - 24][j] = 0.f;
        else sB[r - 48][j] = 0.f;
    }
    int d = tid >> 4, s = tid & 15;
    float A = -__expf(alogs[(k * PERK + d) * DST + s]);
    float P = 1.f, S = 0.f;
    #pragma unroll 1
    for (int si = 0; si < 2; ++si) {
        int wsel = subchunk_wsel(sel, b, k, t, si);
        const float* gbase = x + (((size_t)b * CC + k) * HH + (wsel >> 5) * 7) * HH + (wsel & 31) * 7;
        for (int idx = tid; idx < PERK * 49; idx += 384) {
            int d2 = idx / 49, j = idx - d2 * 49;
            int pix = (k >= 2) ? 48 - j : j;
            int q7 = pix / 7, r7 = pix - q7 * 7;
            int wi = (k & 1) ? r7 : q7;
            int wj = (k & 1) ? q7 : r7;
            sxs[d2][j] = gbase[(size_t)d2 * 4 * HH * HH + wi * HH + wj];
        }
        __syncthreads();
        // fused projection: rows 0..23 -> softplus(Weff*xs+bias)=delta, rows 24..39 -> B
        for (int idx = tid; idx < 40 * NG; idx += 384) {
            int row = idx / NG, g = idx - row * NG; int j = g * 4;
            float bs = (row < PERK) ? sbias[row] : 0.f;
            float ax = bs, ay = bs, az = bs, aw = bs;
            #pragma unroll
            for (int d2 = 0; d2 < PERK; ++d2) {
                float w = swt[row * PERK + d2];
                float4 v = *(const float4*)&sxs[d2][j];
                ax += w * v.x; ay += w * v.y; az += w * v.z; aw += w * v.w;
            }
            float* dst;
            if (row < PERK) {
                ax = softplus_f(ax); ay = softplus_f(ay); az = softplus_f(az); aw = softplus_f(aw);
                dst = &sdelta[row][j];
            } else dst = &sB[row - PERK][j];
            if (g < 12) { float4 o = {ax, ay, az, aw}; *(float4*)dst = o; }
            else dst[0] = ax;
        }
        __syncthreads();
        for (int g = 0; g < NG; ++g) {
            int j = g * 4;
            float4 dl4 = *(const float4*)&sdelta[d][j];   // pads = 0
            float4 xs4 = *(const float4*)&sxs[d][j];      // pads = 0
            float4 B4  = *(const float4*)&sB[s][j];       // pads = 0
            float aa;
            aa = __expf(dl4.x * A); S = aa * S + (dl4.x * xs4.x) * B4.x; P *= aa;
            aa = __expf(dl4.y * A); S = aa * S + (dl4.y * xs4.y) * B4.y; P *= aa;
            aa = __expf(dl4.z * A); S = aa * S + (dl4.z * xs4.z) * B4.z; P *= aa;
            aa = __expf(dl4.w * A); S = aa * S + (dl4.w * xs4.w) * B4.w; P *= aa;
        }
        __syncthreads();   // protect LDS for next sub-chunk
    }
    size_t cidx = (size_t)blk * 384 + tid;
    carrP[cidx] = P; carrS[cidx] = S;
}

// -------- K5: carry scan across chunks (hin may alias carrP: read-before-write) --------
__global__ void k_carry(const float* carrP, const float* carrS, float* hin) {
    int gid = blockIdx.x * blockDim.x + threadIdx.x;   // 12288
    int bk = gid / 384, ds = gid - bk * 384;
    float Hv = 0.f;
    for (int t = 0; t < TCH; ++t) {
        size_t idx = ((size_t)bk * TCH + t) * 384 + ds;
        float pv = carrP[idx], sv = carrS[idx];
        hin[idx] = Hv;
        Hv = pv * Hv + sv;
    }
}

// -------- K6: base output: x*(1+p) unselected, x selected --------
__global__ __launch_bounds__(64) void k_base(const float* __restrict__ x,
        const float* __restrict__ probs, const int* __restrict__ rank,
        float* __restrict__ out) {
    int wr = blockIdx.x % NHW; int bc = blockIdx.x / NHW;
    int b = bc / CC;
    __shared__ float buf[7 * HH];
    __shared__ float fmul[NHW];
    int tid = threadIdx.x;
    const float* xp = x + ((size_t)bc * HH + wr * 7) * HH;
    for (int i = tid; i < 7 * HH; i += 64) buf[i] = xp[i];
    if (tid < NHW) {
        int w = wr * NHW + tid;
        fmul[tid] = (rank[b * NWIN + w] < TOPK) ? 1.0f : (1.0f + probs[b * NWIN + w]);
    }
    __syncthreads();
    int c = bc - b * CC;
    for (int idx = tid; idx < NHW * 49; idx += 64) {
        int wc = idx / 49, r = idx - wc * 49;
        int ri = r / 7, rj = r - ri * 7;
        float v = buf[ri * HH + wc * 7 + rj];
        int w = wr * NHW + wc;
        out[(((size_t)b * NWIN + w) * CC + c) * 49 + r] = v * fmul[wc];
    }
}

// -------- K7: phase-3 scan with carry-in; y written DENSE in scan order (coalesced) --------
__global__ __launch_bounds__(384, 8) void k_scan(
        const float* __restrict__ x, const float* __restrict__ wcomb,
        const float* __restrict__ dtb, const float* __restrict__ alogs,
        const float* __restrict__ dsv, const int* __restrict__ sel,
        const float* __restrict__ hin, float* __restrict__ yws) {
    __shared__ __attribute__((aligned(16))) float sxs[PERK][LCP];
    __shared__ __attribute__((aligned(16))) float sdelta[PERK][LCP];  // doubles as y after recurrence
    __shared__ __attribute__((aligned(16))) float sB[DST][LCP];
    __shared__ __attribute__((aligned(16))) float sC[DST][LCP];
    __shared__ float swt[56 * PERK];
    __shared__ float sbias[PERK];
    int blk = blockIdx.x;
    int t = blk % TCH; int bk = blk / TCH; int k = bk & 3; int b = bk >> 2;
    int tid = threadIdx.x;
    for (int i = tid; i < 56 * PERK; i += 384) swt[i] = wcomb[k * (56 * PERK) + i];
    if (tid < PERK) sbias[tid] = dtb[k * PERK + tid];
    if (tid < 240) {                    // zero pad columns 49..51
        int r = tid / 3, j = 49 + tid % 3;
        if (r < 24) sxs[r][j] = 0.f;
        else if (r < 48) sdelta[r - 24][j] = 0.f;
        else if (r < 64) sB[r - 48][j] = 0.f;
        else sC[r - 64][j] = 0.f;
    }
    int d = tid >> 4, s = tid & 15;
    float A = -__expf(alogs[(k * PERK + d) * DST + s]);
    float Dsr = dsv[k * PERK + d];
    size_t cidx = (size_t)blk * 384 + tid;
    float h = hin[cidx];
    #pragma unroll 1
    for (int si = 0; si < 2; ++si) {
        int l0 = t * LC + si * 49;
        int wsel = subchunk_wsel(sel, b, k, t, si);
        const float* gbase = x + (((size_t)b * CC + k) * HH + (wsel >> 5) * 7) * HH + (wsel & 31) * 7;
        for (int idx = tid; idx < PERK * 49; idx += 384) {
            int d2 = idx / 49, j = idx - d2 * 49;
            int pix = (k >= 2) ? 48 - j : j;
            int q7 = pix / 7, r7 = pix - q7 * 7;
            int wi = (k & 1) ? r7 : q7;
            int wj = (k & 1) ? q7 : r7;
            sxs[d2][j] = gbase[(size_t)d2 * 4 * HH * HH + wi * HH + wj];
        }
        __syncthreads();
        // fused projection: 0..23 delta (softplus), 24..39 B, 40..55 C
        for (int idx = tid; idx < 56 * NG; idx += 384) {
            int row = idx / NG, g = idx - row * NG; int j = g * 4;
            float bs = (row < PERK) ? sbias[row] : 0.f;
            float ax = bs, ay = bs, az = bs, aw = bs;
            #pragma unroll
            for (int d2 = 0; d2 < PERK; ++d2) {
                float w = swt[row * PERK + d2];
                float4 v = *(const float4*)&sxs[d2][j];
                ax += w * v.x; ay += w * v.y; az += w * v.z; aw += w * v.w;
            }
            float* dst;
            if (row < PERK) {
                ax = softplus_f(ax); ay = softplus_f(ay); az = softplus_f(az); aw = softplus_f(aw);
                dst = &sdelta[row][j];
            } else if (row < PERK + DST) dst = &sB[row - PERK][j];
            else dst = &sC[row - PERK - DST][j];
            if (g < 12) { float4 o = {ax, ay, az, aw}; *(float4*)dst = o; }
            else dst[0] = ax;
        }
        __syncthreads();
        for (int g = 0; g < NG; ++g) {
            int j = g * 4;
            float4 dl4 = *(const float4*)&sdelta[d][j];
            float4 xs4 = *(const float4*)&sxs[d][j];
            float4 B4  = *(const float4*)&sB[s][j];
            float4 C4  = *(const float4*)&sC[s][j];
            float aa, part;
            aa = __expf(dl4.x * A); h = aa * h + (dl4.x * xs4.x) * B4.x;
            part = h * C4.x;
            ROR_ADD(part, 0x121); ROR_ADD(part, 0x122); ROR_ADD(part, 0x124); ROR_ADD(part, 0x128);
            if (s == 0) sdelta[d][j] = part + xs4.x * Dsr;
            aa = __expf(dl4.y * A); h = aa * h + (dl4.y * xs4.y) * B4.y;
            part = h * C4.y;
            ROR_ADD(part, 0x121); ROR_ADD(part, 0x122); ROR_ADD(part, 0x124); ROR_ADD(part, 0x128);
            if (s == 0 && j + 1 < 49) sdelta[d][j + 1] = part + xs4.y * Dsr;
            aa = __expf(dl4.z * A); h = aa * h + (dl4.z * xs4.z) * B4.z;
            part = h * C4.z;
            ROR_ADD(part, 0x121); ROR_ADD(part, 0x122); ROR_ADD(part, 0x124); ROR_ADD(part, 0x128);
            if (s == 0 && j + 2 < 49) sdelta[d][j + 2] = part + xs4.z * Dsr;
            aa = __expf(dl4.w * A); h = aa * h + (dl4.w * xs4.w) * B4.w;
            part = h * C4.w;
            ROR_ADD(part, 0x121); ROR_ADD(part, 0x122); ROR_ADD(part, 0x124); ROR_ADD(part, 0x128);
            if (s == 0 && j + 3 < 49) sdelta[d][j + 3] = part + xs4.w * Dsr;
        }
        __syncthreads();
        // dense coalesced write: yws[bk][l0+j][d2] — 4704 contiguous floats per sub-chunk
        float* ybase = yws + ((size_t)bk * LL + l0) * PERK;
        for (int idx = tid; idx < PERK * 49; idx += 384) {
            int j = idx / PERK, d2 = idx - j * PERK;
            ybase[idx] = sdelta[d2][j];
        }
        __syncthreads();   // protect sdelta/sxs for next sub-chunk
    }
}

// -------- K8: per-selected-window gather of y + contiguous RMW into out --------
__global__ __launch_bounds__(256) void k_yadd(const float* __restrict__ yws,
        const int* __restrict__ sel, const float* __restrict__ rw,
        float* __restrict__ out) {
    __shared__ float ytile[CC * 49];
    int qo = blockIdx.x & 255; int b = blockIdx.x >> 8;
    int wsel = sel[b * TOPK + qo];
    float p = rw[b * TOPK + qo];
    for (int idx = threadIdx.x; idx < CC * 49; idx += 256) {
        int k = idx / 1176; int r1 = idx - k * 1176;
        int u = r1 / 168;   int r2 = r1 - u * 168;
        int wj = r2 / 24;   int d = r2 - wj * 24;
        int rest = qo * 7 + u;
        int b2 = rest & 15; int aw = rest >> 4;
        int wi = aw % 7;    int a = aw / 7;
        int q   = (k & 1) ? (b2 * 16 + a) : (a * 16 + b2);
        int pix = (k & 1) ? (wj * 7 + wi) : (wi * 7 + wj);
        int uu = q * 49 + pix;
        int l = (k >= 2) ? (LL - 1 - uu) : uu;
        ytile[(k * PERK + d) * 49 + u * 7 + wj] = yws[((size_t)(b * 4 + k) * LL + l) * PERK + d];
    }
    __syncthreads();
    float* ob = out + ((size_t)(b * NWIN + wsel) * CC) * 49;
    for (int e = threadIdx.x; e < CC * 49; e += 256) ob[e] += p * ytile[e];
}

extern "C" void kernel_launch(void* const* d_in, const int* in_sizes, int n_in,
                              void* d_out, int out_size, void* d_ws, size_t ws_size,
                              hipStream_t stream) {
    const float* x   = (const float*)d_in[0];
    const float* w1  = (const float*)d_in[1];
    const float* b1  = (const float*)d_in[2];
    const float* w2  = (const float*)d_in[3];
    const float* b2  = (const float*)d_in[4];
    const float* xpw = (const float*)d_in[5];
    const float* dtw = (const float*)d_in[6];
    const float* dtb = (const float*)d_in[7];
    const float* alg = (const float*)d_in[8];
    const float* dsv = (const float*)d_in[9];
    float* out = (float*)d_out;
    float* ws  = (float*)d_ws;

    float* pooled = ws + OFF_POOL;
    float* logits = ws + OFF_LOG;
    float* probs  = ws + OFF_PROB;
    float* rwv    = ws + OFF_RW;
    int*   rank   = (int*)(ws + OFF_RANK);
    int*   sel    = (int*)(ws + OFF_SEL);
    float* wcomb  = ws + OFF_WEFF;
    float* cP  = ws + OFF_CP;       // also hin after k_carry
    float* cS  = ws + OFF_CS;
    float* yws = ws + OFF_YWS;

    k_weff  <<<(4 * 56 * PERK + 255) / 256, 256, 0, stream>>>(xpw, dtw, wcomb);
    k_pool  <<<BBATCH * CC, 256, 0, stream>>>(x, pooled);
    k_router<<<BBATCH * NWIN / 256, 256, 0, stream>>>(pooled, w1, b1, w2, b2, logits);
    k_soft  <<<BBATCH, 1024, 0, stream>>>(logits, probs);
    k_rank2 <<<BBATCH * 16, 64, 0, stream>>>(probs, rwv, rank, sel);
    k_phase1<<<NBK * TCH, 384, 0, stream>>>(x, wcomb, dtb, alg, sel, cP, cS);
    k_carry <<<48, 256, 0, stream>>>(cP, cS, cP);     // hin aliases cP (read-before-write)
    k_base  <<<BBATCH * CC * NHW, 64, 0, stream>>>(x, probs, rank, out);
    k_scan  <<<NBK * TCH, 384, 0, stream>>>(x, wcomb, dtb, alg, dsv, sel, cP, yws);
    k_yadd  <<<BBATCH * TOPK, 256, 0, stream>>>(yws, sel, rwv, out);
}

// Round 5
// 575.597 us; speedup vs baseline: 2.6478x; 2.5276x over previous
//
#include <hip/hip_runtime.h>
#include <math.h>

// Problem constants
#define BBATCH 8
#define CC 96
#define HH 224
#define NHW 32            // 224/7 windows per side
#define NWIN 1024
#define TOPK 256
#define PERK 24
#define DST 16
#define DTR 6
#define LL 12544          // 256*49
#define LC 98             // chunk length per block (2 sub-chunks = 2 scan windows)
#define LCP 52            // padded sub-chunk row length (49 used + 3 zero pad)
#define NG 13             // float4 groups per row
#define TCH 128           // chunks per (b,k): 128*98 = 12544
#define NBK 32            // B*4 directions

// workspace offsets (floats) — total 13,600,000 floats = 54.4 MB
#define OFF_POOL 0
#define OFF_LOG  786432
#define OFF_PROB 794624
#define OFF_RW   802816
#define OFF_RANK 804864
#define OFF_SEL  813056
#define OFF_WEFF 815104
#define OFF_CP   820480      // 1,572,864 floats; ALSO reused as hin (read-before-write in k_carry)
#define OFF_CS   2393344     // 1,572,864 floats
#define OFF_YWS  3966208     // 9,633,792 floats: y_ws[bk][l][d], d innermost

// DPP row_ror:N add — 16-lane full-sum reduction on the VALU pipe (not DS)
#define ROR_ADD(v, CTRL) \
    v += __int_as_float(__builtin_amdgcn_update_dpp(0, __float_as_int(v), CTRL, 0xf, 0xf, true))

// -------- K0: fold dt_proj into x_proj: Wcomb[k][56][24] --------
__global__ void k_weff(const float* __restrict__ xpw, const float* __restrict__ dtw,
                       float* __restrict__ wcomb) {
    int i = blockIdx.x * blockDim.x + threadIdx.x;
    if (i >= 4 * 56 * PERK) return;
    int k = i / (56 * PERK), rem = i - k * (56 * PERK);
    int row = rem / PERK, c = rem - row * PERK;
    float v;
    if (row < PERK) {
        v = 0.f;
        #pragma unroll
        for (int r = 0; r < DTR; ++r)
            v += dtw[(k * PERK + row) * DTR + r] * xpw[(k * 38 + r) * PERK + c];
    } else {
        v = xpw[(k * 38 + (row - PERK + DTR)) * PERK + c];
    }
    wcomb[i] = v;
}

// -------- K1: window pooling: pooledT[b][c][w] --------
__global__ void k_pool(const float* __restrict__ x, float* __restrict__ pooled) {
    int bc = blockIdx.x;                 // b*96+c
    const float* xp = x + (size_t)bc * HH * HH;
    float* pp = pooled + (size_t)bc * NWIN;
    for (int w = threadIdx.x; w < NWIN; w += blockDim.x) {
        int wr = w >> 5, wc = w & 31;
        const float* base = xp + (wr * 7) * HH + wc * 7;
        float s = 0.f;
        #pragma unroll
        for (int i = 0; i < 7; ++i) {
            #pragma unroll
            for (int j = 0; j < 7; ++j) s += base[i * HH + j];
        }
        pp[w] = s * (1.0f / 49.0f);
    }
}

// -------- K2: router MLP -> logits --------
__global__ void k_router(const float* __restrict__ pooled,
                         const float* __restrict__ w1, const float* __restrict__ b1,
                         const float* __restrict__ w2, const float* __restrict__ b2,
                         float* __restrict__ logits) {
    __shared__ float sw1[PERK * CC];
    __shared__ float sb1[PERK];
    __shared__ float sw2[PERK];
    for (int i = threadIdx.x; i < PERK * CC; i += blockDim.x) sw1[i] = w1[i];
    if (threadIdx.x < PERK) { sb1[threadIdx.x] = b1[threadIdx.x]; sw2[threadIdx.x] = w2[threadIdx.x]; }
    __syncthreads();
    int gid = blockIdx.x * blockDim.x + threadIdx.x;   // 8192 threads
    int b = gid >> 10, w = gid & 1023;
    float hid[PERK];
    #pragma unroll
    for (int j = 0; j < PERK; ++j) hid[j] = sb1[j];
    const float* pp = pooled + (size_t)b * CC * NWIN + w;
    for (int c = 0; c < CC; ++c) {
        float pv = pp[(size_t)c * NWIN];
        #pragma unroll
        for (int j = 0; j < PERK; ++j) hid[j] += pv * sw1[j * CC + c];
    }
    float lg = b2[0];
    #pragma unroll
    for (int j = 0; j < PERK; ++j) {
        float hv = hid[j];
        float g = 0.5f * hv * (1.0f + erff(hv * 0.7071067811865476f));
        lg += g * sw2[j];
    }
    logits[gid] = lg;
}

// -------- K3a: softmax over 1024 windows --------
__global__ void k_soft(const float* __restrict__ logits, float* __restrict__ probs) {
    __shared__ float red[NWIN];
    int b = blockIdx.x, t = threadIdx.x;
    float lg = logits[b * NWIN + t];
    red[t] = lg; __syncthreads();
    for (int o = 512; o > 0; o >>= 1) { if (t < o) red[t] = fmaxf(red[t], red[t + o]); __syncthreads(); }
    float mx = red[0]; __syncthreads();
    float e = expf(lg - mx);
    red[t] = e; __syncthreads();
    for (int o = 512; o > 0; o >>= 1) { if (t < o) red[t] += red[t + o]; __syncthreads(); }
    probs[b * NWIN + t] = e / red[0];
}

// -------- K3b: stable descending rank (distributed over 128 blocks) --------
__global__ __launch_bounds__(64) void k_rank2(const float* __restrict__ probs,
        float* __restrict__ rw, int* __restrict__ rank, int* __restrict__ sel) {
    __shared__ __attribute__((aligned(16))) float sp[NWIN];
    int b = blockIdx.x >> 4, slice = blockIdx.x & 15;
    int tid = threadIdx.x;
    for (int i = tid; i < NWIN / 4; i += 64)
        ((float4*)sp)[i] = ((const float4*)(probs + (size_t)b * NWIN))[i];
    __syncthreads();
    int w = slice * 64 + tid;
    float p = sp[w];
    int r = 0;
    for (int j = 0; j < NWIN; j += 4) {
        float4 pj = *(const float4*)&sp[j];
        r += (int)((pj.x > p) || (pj.x == p && (j + 0) < w));
        r += (int)((pj.y > p) || (pj.y == p && (j + 1) < w));
        r += (int)((pj.z > p) || (pj.z == p && (j + 2) < w));
        r += (int)((pj.w > p) || (pj.w == p && (j + 3) < w));
    }
    rank[b * NWIN + w] = r;
    if (r < TOPK) { sel[b * TOPK + r] = w; rw[b * TOPK + r] = p; }
}

// softplus
__device__ __forceinline__ float softplus_f(float v) {
    return fmaxf(v, 0.f) + log1pf(__expf(-fabsf(v)));
}

// per-sub-chunk selected-window lookup: sub-chunk = exactly one scan window
__device__ __forceinline__ int subchunk_wsel(const int* sel, int b, int k, int t, int si) {
    int qscan = 2 * t + si;
    if (k >= 2) qscan = 255 - qscan;
    int selidx = (k & 1) ? (((qscan & 15) << 4) | (qscan >> 4)) : qscan;
    return sel[b * TOPK + selidx];
}

// -------- K4: phase-1 chunk scan: per-chunk (P = prod a, S = local state) --------
__global__ __launch_bounds__(384, 4) void k_phase1(
        const float* __restrict__ x, const float* __restrict__ wcomb,
        const float* __restrict__ dtb, const float* __restrict__ alogs,
        const int* __restrict__ sel,
        float* __restrict__ carrP, float* __restrict__ carrS) {
    __shared__ __attribute__((aligned(16))) float sxs[PERK][LCP];
    __shared__ __attribute__((aligned(16))) float sdelta[PERK][LCP];
    __shared__ __attribute__((aligned(16))) float sB[DST][LCP];
    __shared__ float swt[40 * PERK];
    __shared__ float sbias[PERK];
    int blk = blockIdx.x;               // bk*TCH + t
    int t = blk % TCH; int bk = blk / TCH; int k = bk & 3; int b = bk >> 2;
    int tid = threadIdx.x;
    for (int i = tid; i < 40 * PERK; i += 384) swt[i] = wcomb[k * (56 * PERK) + i];
    if (tid < PERK) sbias[tid] = dtb[k * PERK + tid];
    if (tid < 192) {                    // zero pad columns 49..51
        int r = tid / 3, j = 49 + tid % 3;
        if (r < 24) sxs[r][j] = 0.f;
        else if (r < 48) sdelta[r - 24][j] = 0.f;
        else sB[r - 48][j] = 0.f;
    }
    int d = tid >> 4, s = tid & 15;
    float A = -__expf(alogs[(k * PERK + d) * DST + s]);
    float P = 1.f, S = 0.f;
    #pragma unroll 1
    for (int si = 0; si < 2; ++si) {
        int wsel = subchunk_wsel(sel, b, k, t, si);
        const float* gbase = x + (((size_t)b * CC + k) * HH + (wsel >> 5) * 7) * HH + (wsel & 31) * 7;
        for (int idx = tid; idx < PERK * 49; idx += 384) {
            int d2 = idx / 49, j = idx - d2 * 49;
            int pix = (k >= 2) ? 48 - j : j;
            int q7 = pix / 7, r7 = pix - q7 * 7;
            int wi = (k & 1) ? r7 : q7;
            int wj = (k & 1) ? q7 : r7;
            sxs[d2][j] = gbase[(size_t)d2 * 4 * HH * HH + wi * HH + wj];
        }
        __syncthreads();
        // fused projection: rows 0..23 -> softplus(Weff*xs+bias)=delta, rows 24..39 -> B
        for (int idx = tid; idx < 40 * NG; idx += 384) {
            int row = idx / NG, g = idx - row * NG; int j = g * 4;
            float bs = (row < PERK) ? sbias[row] : 0.f;
            float ax = bs, ay = bs, az = bs, aw = bs;
            #pragma unroll
            for (int d2 = 0; d2 < PERK; ++d2) {
                float w = swt[row * PERK + d2];
                float4 v = *(const float4*)&sxs[d2][j];
                ax += w * v.x; ay += w * v.y; az += w * v.z; aw += w * v.w;
            }
            float* dst;
            if (row < PERK) {
                ax = softplus_f(ax); ay = softplus_f(ay); az = softplus_f(az); aw = softplus_f(aw);
                dst = &sdelta[row][j];
            } else dst = &sB[row - PERK][j];
            if (g < 12) { float4 o = {ax, ay, az, aw}; *(float4*)dst = o; }
            else dst[0] = ax;
        }
        __syncthreads();
        for (int g = 0; g < NG; ++g) {
            int j = g * 4;
            float4 dl4 = *(const float4*)&sdelta[d][j];   // pads = 0
            float4 xs4 = *(const float4*)&sxs[d][j];      // pads = 0
            float4 B4  = *(const float4*)&sB[s][j];       // pads = 0
            float aa;
            aa = __expf(dl4.x * A); S = aa * S + (dl4.x * xs4.x) * B4.x; P *= aa;
            aa = __expf(dl4.y * A); S = aa * S + (dl4.y * xs4.y) * B4.y; P *= aa;
            aa = __expf(dl4.z * A); S = aa * S + (dl4.z * xs4.z) * B4.z; P *= aa;
            aa = __expf(dl4.w * A); S = aa * S + (dl4.w * xs4.w) * B4.w; P *= aa;
        }
        __syncthreads();   // protect LDS for next sub-chunk
    }
    size_t cidx = (size_t)blk * 384 + tid;
    carrP[cidx] = P; carrS[cidx] = S;
}

// -------- K5: carry scan across chunks (hin may alias carrP: read-before-write) --------
__global__ void k_carry(const float* carrP, const float* carrS, float* hin) {
    int gid = blockIdx.x * blockDim.x + threadIdx.x;   // 12288
    int bk = gid / 384, ds = gid - bk * 384;
    float Hv = 0.f;
    for (int t = 0; t < TCH; ++t) {
        size_t idx = ((size_t)bk * TCH + t) * 384 + ds;
        float pv = carrP[idx], sv = carrS[idx];
        hin[idx] = Hv;
        Hv = pv * Hv + sv;
    }
}

// -------- K6: base output: x*(1+p) unselected, x selected --------
__global__ __launch_bounds__(64) void k_base(const float* __restrict__ x,
        const float* __restrict__ probs, const int* __restrict__ rank,
        float* __restrict__ out) {
    int wr = blockIdx.x % NHW; int bc = blockIdx.x / NHW;
    int b = bc / CC;
    __shared__ float buf[7 * HH];
    __shared__ float fmul[NHW];
    int tid = threadIdx.x;
    const float* xp = x + ((size_t)bc * HH + wr * 7) * HH;
    for (int i = tid; i < 7 * HH; i += 64) buf[i] = xp[i];
    if (tid < NHW) {
        int w = wr * NHW + tid;
        fmul[tid] = (rank[b * NWIN + w] < TOPK) ? 1.0f : (1.0f + probs[b * NWIN + w]);
    }
    __syncthreads();
    int c = bc - b * CC;
    for (int idx = tid; idx < NHW * 49; idx += 64) {
        int wc = idx / 49, r = idx - wc * 49;
        int ri = r / 7, rj = r - ri * 7;
        float v = buf[ri * HH + wc * 7 + rj];
        int w = wr * NHW + wc;
        out[(((size_t)b * NWIN + w) * CC + c) * 49 + r] = v * fmul[wc];
    }
}

// -------- K7: phase-3 scan with carry-in; y written DENSE in scan order (coalesced) --------
__global__ __launch_bounds__(384, 4) void k_scan(
        const float* __restrict__ x, const float* __restrict__ wcomb,
        const float* __restrict__ dtb, const float* __restrict__ alogs,
        const float* __restrict__ dsv, const int* __restrict__ sel,
        const float* __restrict__ hin, float* __restrict__ yws) {
    __shared__ __attribute__((aligned(16))) float sxs[PERK][LCP];
    __shared__ __attribute__((aligned(16))) float sdelta[PERK][LCP];  // doubles as y after recurrence
    __shared__ __attribute__((aligned(16))) float sB[DST][LCP];
    __shared__ __attribute__((aligned(16))) float sC[DST][LCP];
    __shared__ float swt[56 * PERK];
    __shared__ float sbias[PERK];
    int blk = blockIdx.x;
    int t = blk % TCH; int bk = blk / TCH; int k = bk & 3; int b = bk >> 2;
    int tid = threadIdx.x;
    for (int i = tid; i < 56 * PERK; i += 384) swt[i] = wcomb[k * (56 * PERK) + i];
    if (tid < PERK) sbias[tid] = dtb[k * PERK + tid];
    if (tid < 240) {                    // zero pad columns 49..51
        int r = tid / 3, j = 49 + tid % 3;
        if (r < 24) sxs[r][j] = 0.f;
        else if (r < 48) sdelta[r - 24][j] = 0.f;
        else if (r < 64) sB[r - 48][j] = 0.f;
        else sC[r - 64][j] = 0.f;
    }
    int d = tid >> 4, s = tid & 15;
    float A = -__expf(alogs[(k * PERK + d) * DST + s]);
    float Dsr = dsv[k * PERK + d];
    size_t cidx = (size_t)blk * 384 + tid;
    float h = hin[cidx];
    #pragma unroll 1
    for (int si = 0; si < 2; ++si) {
        int l0 = t * LC + si * 49;
        int wsel = subchunk_wsel(sel, b, k, t, si);
        const float* gbase = x + (((size_t)b * CC + k) * HH + (wsel >> 5) * 7) * HH + (wsel & 31) * 7;
        for (int idx = tid; idx < PERK * 49; idx += 384) {
            int d2 = idx / 49, j = idx - d2 * 49;
            int pix = (k >= 2) ? 48 - j : j;
            int q7 = pix / 7, r7 = pix - q7 * 7;
            int wi = (k & 1) ? r7 : q7;
            int wj = (k & 1) ? q7 : r7;
            sxs[d2][j] = gbase[(size_t)d2 * 4 * HH * HH + wi * HH + wj];
        }
        __syncthreads();
        // fused projection: 0..23 delta (softplus), 24..39 B, 40..55 C
        for (int idx = tid; idx < 56 * NG; idx += 384) {
            int row = idx / NG, g = idx - row * NG; int j = g * 4;
            float bs = (row < PERK) ? sbias[row] : 0.f;
            float ax = bs, ay = bs, az = bs, aw = bs;
            #pragma unroll
            for (int d2 = 0; d2 < PERK; ++d2) {
                float w = swt[row * PERK + d2];
                float4 v = *(const float4*)&sxs[d2][j];
                ax += w * v.x; ay += w * v.y; az += w * v.z; aw += w * v.w;
            }
            float* dst;
            if (row < PERK) {
                ax = softplus_f(ax); ay = softplus_f(ay); az = softplus_f(az); aw = softplus_f(aw);
                dst = &sdelta[row][j];
            } else if (row < PERK + DST) dst = &sB[row - PERK][j];
            else dst = &sC[row - PERK - DST][j];
            if (g < 12) { float4 o = {ax, ay, az, aw}; *(float4*)dst = o; }
            else dst[0] = ax;
        }
        __syncthreads();
        for (int g = 0; g < NG; ++g) {
            int j = g * 4;
            float4 dl4 = *(const float4*)&sdelta[d][j];
            float4 xs4 = *(const float4*)&sxs[d][j];
            float4 B4  = *(const float4*)&sB[s][j];
            float4 C4  = *(const float4*)&sC[s][j];
            float aa, part;
            aa = __expf(dl4.x * A); h = aa * h + (dl4.x * xs4.x) * B4.x;
            part = h * C4.x;
            ROR_ADD(part, 0x121); ROR_ADD(part, 0x122); ROR_ADD(part, 0x124); ROR_ADD(part, 0x128);
            if (s == 0) sdelta[d][j] = part + xs4.x * Dsr;
            aa = __expf(dl4.y * A); h = aa * h + (dl4.y * xs4.y) * B4.y;
            part = h * C4.y;
            ROR_ADD(part, 0x121); ROR_ADD(part, 0x122); ROR_ADD(part, 0x124); ROR_ADD(part, 0x128);
            if (s == 0 && j + 1 < 49) sdelta[d][j + 1] = part + xs4.y * Dsr;
            aa = __expf(dl4.z * A); h = aa * h + (dl4.z * xs4.z) * B4.z;
            part = h * C4.z;
            ROR_ADD(part, 0x121); ROR_ADD(part, 0x122); ROR_ADD(part, 0x124); ROR_ADD(part, 0x128);
            if (s == 0 && j + 2 < 49) sdelta[d][j + 2] = part + xs4.z * Dsr;
            aa = __expf(dl4.w * A); h = aa * h + (dl4.w * xs4.w) * B4.w;
            part = h * C4.w;
            ROR_ADD(part, 0x121); ROR_ADD(part, 0x122); ROR_ADD(part, 0x124); ROR_ADD(part, 0x128);
            if (s == 0 && j + 3 < 49) sdelta[d][j + 3] = part + xs4.w * Dsr;
        }
        __syncthreads();
        // dense coalesced write: yws[bk][l0+j][d2] — 4704 contiguous floats per sub-chunk
        float* ybase = yws + ((size_t)bk * LL + l0) * PERK;
        for (int idx = tid; idx < PERK * 49; idx += 384) {
            int j = idx / PERK, d2 = idx - j * PERK;
            ybase[idx] = sdelta[d2][j];
        }
        __syncthreads();   // protect sdelta/sxs for next sub-chunk
    }
}

// -------- K8: per-selected-window gather of y + contiguous RMW into out --------
__global__ __launch_bounds__(256) void k_yadd(const float* __restrict__ yws,
        const int* __restrict__ sel, const float* __restrict__ rw,
        float* __restrict__ out) {
    __shared__ float ytile[CC * 49];
    int qo = blockIdx.x & 255; int b = blockIdx.x >> 8;
    int wsel = sel[b * TOPK + qo];
    float p = rw[b * TOPK + qo];
    for (int idx = threadIdx.x; idx < CC * 49; idx += 256) {
        int k = idx / 1176; int r1 = idx - k * 1176;
        int u = r1 / 168;   int r2 = r1 - u * 168;
        int wj = r2 / 24;   int d = r2 - wj * 24;
        int rest = qo * 7 + u;
        int b2 = rest & 15; int aw = rest >> 4;
        int wi = aw % 7;    int a = aw / 7;
        int q   = (k & 1) ? (b2 * 16 + a) : (a * 16 + b2);
        int pix = (k & 1) ? (wj * 7 + wi) : (wi * 7 + wj);
        int uu = q * 49 + pix;
        int l = (k >= 2) ? (LL - 1 - uu) : uu;
        ytile[(k * PERK + d) * 49 + u * 7 + wj] = yws[((size_t)(b * 4 + k) * LL + l) * PERK + d];
    }
    __syncthreads();
    float* ob = out + ((size_t)(b * NWIN + wsel) * CC) * 49;
    for (int e = threadIdx.x; e < CC * 49; e += 256) ob[e] += p * ytile[e];
}

extern "C" void kernel_launch(void* const* d_in, const int* in_sizes, int n_in,
                              void* d_out, int out_size, void* d_ws, size_t ws_size,
                              hipStream_t stream) {
    const float* x   = (const float*)d_in[0];
    const float* w1  = (const float*)d_in[1];
    const float* b1  = (const float*)d_in[2];
    const float* w2  = (const float*)d_in[3];
    const float* b2  = (const float*)d_in[4];
    const float* xpw = (const float*)d_in[5];
    const float* dtw = (const float*)d_in[6];
    const float* dtb = (const float*)d_in[7];
    const float* alg = (const float*)d_in[8];
    const float* dsv = (const float*)d_in[9];
    float* out = (float*)d_out;
    float* ws  = (float*)d_ws;

    float* pooled = ws + OFF_POOL;
    float* logits = ws + OFF_LOG;
    float* probs  = ws + OFF_PROB;
    float* rwv    = ws + OFF_RW;
    int*   rank   = (int*)(ws + OFF_RANK);
    int*   sel    = (int*)(ws + OFF_SEL);
    float* wcomb  = ws + OFF_WEFF;
    float* cP  = ws + OFF_CP;       // also hin after k_carry
    float* cS  = ws + OFF_CS;
    float* yws = ws + OFF_YWS;

    k_weff  <<<(4 * 56 * PERK + 255) / 256, 256, 0, stream>>>(xpw, dtw, wcomb);
    k_pool  <<<BBATCH * CC, 256, 0, stream>>>(x, pooled);
    k_router<<<BBATCH * NWIN / 256, 256, 0, stream>>>(pooled, w1, b1, w2, b2, logits);
    k_soft  <<<BBATCH, 1024, 0, stream>>>(logits, probs);
    k_rank2 <<<BBATCH * 16, 64, 0, stream>>>(probs, rwv, rank, sel);
    k_phase1<<<NBK * TCH, 384, 0, stream>>>(x, wcomb, dtb, alg, sel, cP, cS);
    k_carry <<<48, 256, 0, stream>>>(cP, cS, cP);     // hin aliases cP (read-before-write)
    k_base  <<<BBATCH * CC * NHW, 64, 0, stream>>>(x, probs, rank, out);
    k_scan  <<<NBK * TCH, 384, 0, stream>>>(x, wcomb, dtb, alg, dsv, sel, cP, yws);
    k_yadd  <<<BBATCH * TOPK, 256, 0, stream>>>(yws, sel, rwv, out);
}